// Round 4
// baseline (363.649 us; speedup 1.0000x reference)
//
#include <hip/hip_runtime.h>

// CQT on gfx950 — LDS-free, barrier-free MFMA pipeline.
//   Wr[b,n] = sum_k kr[b,k]*cos(2pi k n/2048) - ki[b,k]*sin(...)
//   Wi[b,n] = sum_k kr[b,k]*sin(...) + ki[b,k]*cos(...)
//   cqt[b,f] = sqrt( (sum_n x[512f+n]*W[2b,n])^2 + (sum_n x[512f+n]*W[2b+1,n])^2 )
// K1 wgemm: Wp[192][2048] bf16, rows 2b=Wr, 2b+1=Wi (pad to 192 with zeros).
//           One 16x16 output tile per wave; A' from kr/ki with sign/select in regs,
//           B = trig computed in regs (no wcos/wsin reads). No LDS, no barriers.
// K2 cqt:   C[192,16381] = Wp @ B, B[k,f]=x[512f+k]. Wave tile 96x64 (mt6 x nt4),
//           A/B fragments loaded DIRECTLY from global (k-contiguous 16B per lane),
//           ping-pong register prefetch, no LDS, no barriers.

#define HOPS 512
#define NBINS 84
#define FREQB 1025
#define FFTLEN 2048
#define NFRAMES 16381
#define KPAD 2112
#define SINBASE 1025
#define ANGC 0.00306796157577128f   // 2*pi/2048

typedef short bf16x8 __attribute__((ext_vector_type(8)));
typedef float f32x4 __attribute__((ext_vector_type(4)));

union U4B8 { uint4 u; bf16x8 v; };

__device__ __forceinline__ unsigned short f32_to_bf16(float f) {
    union { float f; unsigned u; } v; v.f = f;
    return (unsigned short)((v.u + 0x7FFFu + ((v.u >> 16) & 1u)) >> 16);
}
__device__ __forceinline__ unsigned pk_bf16(float lo, float hi) {
    return (unsigned)f32_to_bf16(lo) | ((unsigned)f32_to_bf16(hi) << 16);
}
__device__ __forceinline__ bf16x8 pack8(const float* s) {
    U4B8 r;
    r.u.x = pk_bf16(s[0], s[1]); r.u.y = pk_bf16(s[2], s[3]);
    r.u.z = pk_bf16(s[4], s[5]); r.u.w = pk_bf16(s[6], s[7]);
    return r.v;
}

// ---------------- Kernel 1: W GEMM, direct ----------------
// grid 12*128 = 1536 blocks x 64 thr (1 wave). Tile: rows m0..m0+15, cols n0..n0+15.
// A'[row][k]: k<=1024: (im? ki : kr)[b][k]; 1025<=k<=2049: (im? kr : -ki)[b][k-1025]; else 0.
// B[k][n]:   k<=1024: cos(2pi k n/2048); 1025<=k<=2049: sin(2pi (k-1025) n/2048); else 0.
__global__ __launch_bounds__(64) void wgemm_kernel(
    const float* __restrict__ kr, const float* __restrict__ ki,
    unsigned short* __restrict__ Wp)
{
    const int l = threadIdx.x;
    const int mt = blockIdx.x % 12, nb = blockIdx.x / 12;
    const int m0 = mt * 16, n0 = nb * 16;
    const int col = l & 15, q = l >> 4;

    const int row = m0 + col;
    const int b = row >> 1, im = row & 1;
    const bool bok = b < NBINS;
    const float* pr = kr + b * FREQB;
    const float* pi = ki + b * FREQB;
    const int n = n0 + col;

    f32x4 acc = {0.f, 0.f, 0.f, 0.f};

    for (int k0 = 0; k0 < KPAD; k0 += 32) {
        const int kb = k0 + q * 8;
        float av[8], bv[8];
        #pragma unroll
        for (int j = 0; j < 8; ++j) {
            int kk = kb + j;
            float a = 0.f, t = 0.f;
            if (kk <= 1024) {
                if (bok) a = im ? pi[kk] : pr[kk];
                int prod = (kk * n) & (FFTLEN - 1);
                t = __cosf((float)prod * ANGC);
            } else if (kk <= 2049) {
                int m = kk - SINBASE;
                if (bok) a = im ? pr[m] : -pi[m];
                int prod = (m * n) & (FFTLEN - 1);
                t = __sinf((float)prod * ANGC);
            }
            av[j] = a; bv[j] = t;
        }
        acc = __builtin_amdgcn_mfma_f32_16x16x32_bf16(pack8(av), pack8(bv), acc, 0, 0, 0);
    }

    // C/D: col = lane&15 (n), row = (lane>>4)*4 + reg
    #pragma unroll
    for (int r = 0; r < 4; ++r) {
        int orow = m0 + q * 4 + r;
        Wp[orow * FFTLEN + n] = f32_to_bf16(acc[r]);
    }
}

// ---------------- Kernel 2: main GEMM, direct ----------------
// grid 512 blocks x 64 thr (1 wave). bid: mg = bid&1 (rows mg*96..+95), f0 = (bid>>1)*64.
// Wave tile 96 x 64: mt=6 (16-row tiles) x nt=4 (16-frame tiles), acc 6*4*4 f32.
// A frag: lane reads bf16x8 = uint4 at Wp[row][k..k+7] (16B aligned, k%8==0).
// B frag: lane reads 2 float4 from x[f*512 + k..k+7], packs to bf16 (masked f>=NFRAMES).
__global__ __launch_bounds__(64) void cqt_kernel(
    const float* __restrict__ x, const unsigned short* __restrict__ Wp,
    float* __restrict__ out)
{
    const int l = threadIdx.x;
    const int mg = blockIdx.x & 1;
    const int f0 = (int)(blockIdx.x >> 1) * 64;
    const int col = l & 15, q = l >> 4;

    const unsigned short* arow[6];
    #pragma unroll
    for (int mt = 0; mt < 6; ++mt)
        arow[mt] = Wp + (mg * 96 + mt * 16 + col) * FFTLEN;

    const float* xrow[4];
    bool fok[4];
    #pragma unroll
    for (int nt = 0; nt < 4; ++nt) {
        int f = f0 + nt * 16 + col;
        fok[nt] = f < NFRAMES;
        xrow[nt] = x + (size_t)(fok[nt] ? f : 0) * HOPS;
    }

    f32x4 acc[6][4];
    #pragma unroll
    for (int mt = 0; mt < 6; ++mt)
        #pragma unroll
        for (int nt = 0; nt < 4; ++nt)
            acc[mt][nt] = (f32x4){0.f, 0.f, 0.f, 0.f};

    bf16x8 A0[6], B0[4], A1[6], B1[4];

    auto loadA = [&](int s, bf16x8* A) {
        int k = s * 32 + q * 8;
        #pragma unroll
        for (int mt = 0; mt < 6; ++mt)
            A[mt] = *(const bf16x8*)(arow[mt] + k);
    };
    auto loadB = [&](int s, bf16x8* B) {
        int k = s * 32 + q * 8;
        #pragma unroll
        for (int nt = 0; nt < 4; ++nt) {
            if (fok[nt]) {
                float4 v0 = *(const float4*)(xrow[nt] + k);
                float4 v1 = *(const float4*)(xrow[nt] + k + 4);
                float s8[8] = {v0.x, v0.y, v0.z, v0.w, v1.x, v1.y, v1.z, v1.w};
                B[nt] = pack8(s8);
            } else {
                U4B8 z; z.u = make_uint4(0, 0, 0, 0);
                B[nt] = z.v;
            }
        }
    };
    auto comp = [&](bf16x8* A, bf16x8* B) {
        #pragma unroll
        for (int mt = 0; mt < 6; ++mt)
            #pragma unroll
            for (int nt = 0; nt < 4; ++nt)
                acc[mt][nt] = __builtin_amdgcn_mfma_f32_16x16x32_bf16(
                    A[mt], B[nt], acc[mt][nt], 0, 0, 0);
    };

    loadA(0, A0); loadB(0, B0);
    for (int s = 0; s < 64; s += 2) {
        loadA(s + 1, A1); loadB(s + 1, B1);   // prefetch next step
        comp(A0, B0);
        int s2 = (s + 2 < 64) ? s + 2 : 63;   // redundant-but-safe tail load
        loadA(s2, A0); loadB(s2, B0);
        comp(A1, B1);
    }

    // epilogue: C/D col = lane&15 (f), row = q*4 + reg. Row pairs (even base) are
    // (Wr,Wi) of bin b0 in regs (x,y) and bin b0+1 in (z,w).
    #pragma unroll
    for (int mt = 0; mt < 6; ++mt) {
        int rb = mg * 96 + mt * 16 + 4 * q;
        int b0 = rb >> 1;
        #pragma unroll
        for (int nt = 0; nt < 4; ++nt) {
            int f = f0 + nt * 16 + col;
            if (f < NFRAMES) {
                f32x4 a = acc[mt][nt];
                if (b0 < NBINS)
                    out[b0 * NFRAMES + f] = sqrtf(a.x * a.x + a.y * a.y);
                if (b0 + 1 < NBINS)
                    out[(b0 + 1) * NFRAMES + f] = sqrtf(a.z * a.z + a.w * a.w);
            }
        }
    }
}

extern "C" void kernel_launch(void* const* d_in, const int* in_sizes, int n_in,
                              void* d_out, int out_size, void* d_ws, size_t ws_size,
                              hipStream_t stream) {
    const float* x  = (const float*)d_in[0];
    // d_in[1] (wcos) / d_in[2] (wsin) unused: trig computed on the fly
    const float* kr = (const float*)d_in[3];
    const float* ki = (const float*)d_in[4];
    float* out = (float*)d_out;

    unsigned short* Wp = (unsigned short*)d_ws;   // 192*2048*2 = 786,432 B

    wgemm_kernel<<<dim3(12 * 128), dim3(64), 0, stream>>>(kr, ki, Wp);
    cqt_kernel<<<dim3(512), dim3(64), 0, stream>>>(x, Wp, out);
}

// Round 5
// 213.780 us; speedup vs baseline: 1.7010x; 1.7010x over previous
//
#include <hip/hip_runtime.h>

// CQT on gfx950 — v5.
//   Wr[b,n] = sum_k kr[b,k]*wcos[k,n] - ki[b,k]*wsin[k,n]
//   Wi[b,n] = sum_k kr[b,k]*wsin[k,n] + ki[b,k]*wcos[k,n]
//   cqt[b,f] = sqrt( (sum_n x[512f+n]*W[2b,n])^2 + (sum_n x[512f+n]*W[2b+1,n])^2 )
// K1 wgemm: Wp[192][2048] bf16 (rows 2b=Wr, 2b+1=Wi, zero-pad to 192).
//   LDS-free/barrier-free; grid 512 x 1 wave; wave = 48 rows x 16 cols, K=2080.
//   A from kr/ki (sign/select in regs, scalar L2 loads); B = coalesced 64B table lines.
// K2 cqt: C[192,16381] = Wp @ B, B[k,f]=x[512f+k]. mfma 32x32x16 (2x intensity),
//   tile 96x64, grid 512 (= 2 blocks/CU), 3 waves, XOR-swizzled LDS, 1 barrier/iter.

#define HOPS 512
#define NBINS 84
#define FREQB 1025
#define FFTLEN 2048
#define NFRAMES 16381
#define LASTF 16380

typedef short bf16x8 __attribute__((ext_vector_type(8)));
typedef float f32x4 __attribute__((ext_vector_type(4)));
typedef float f32x16 __attribute__((ext_vector_type(16)));

union U4B8 { uint4 u; bf16x8 v; };

__device__ __forceinline__ unsigned short f32_to_bf16(float f) {
    union { float f; unsigned u; } v; v.f = f;
    return (unsigned short)((v.u + 0x7FFFu + ((v.u >> 16) & 1u)) >> 16);
}
__device__ __forceinline__ unsigned pk_bf16(float lo, float hi) {
    return (unsigned)f32_to_bf16(lo) | ((unsigned)f32_to_bf16(hi) << 16);
}
__device__ __forceinline__ bf16x8 pack8(const float* s) {
    U4B8 r;
    r.u.x = pk_bf16(s[0], s[1]); r.u.y = pk_bf16(s[2], s[3]);
    r.u.z = pk_bf16(s[4], s[5]); r.u.w = pk_bf16(s[6], s[7]);
    return r.v;
}

// ---------------- Kernel 1: W GEMM (tables, LDS-free) ----------------
// grid 512 x 64: bid -> n-tile (bid>>2)*16, m-quarter (bid&3)*48. 16x16x32 MFMA.
// A'[row][k]: k<=1024: (im?ki:kr)[b][k]; k in [1025,2049]: (im?kr:-ki)[b][k-1025].
// B[k][n]:   k<=1024: wcos[k][n];        k in [1025,2049]: wsin[k-1025][n].
__global__ __launch_bounds__(64) void wgemm_kernel(
    const float* __restrict__ wcos, const float* __restrict__ wsin,
    const float* __restrict__ kr, const float* __restrict__ ki,
    unsigned short* __restrict__ Wp)
{
    const int l = threadIdx.x;
    const int col = l & 15, q = l >> 4;
    const int n0 = (int)(blockIdx.x >> 2) * 16;
    const int mq = blockIdx.x & 3;
    const int nn = n0 + col;

    const float* cp[3]; const float* sp[3];
    float cs[3], ss[3];
    #pragma unroll
    for (int mt = 0; mt < 3; ++mt) {
        int row = mq * 48 + mt * 16 + col;
        int b = row >> 1, im = row & 1;
        float bokf = (b < NBINS) ? 1.f : 0.f;
        int bc = (b < NBINS) ? b : 0;
        cp[mt] = (im ? ki : kr) + (size_t)bc * FREQB;  // cos-region A source
        sp[mt] = (im ? kr : ki) + (size_t)bc * FREQB;  // sin-region A source
        cs[mt] = bokf;
        ss[mt] = im ? bokf : -bokf;
    }

    f32x4 acc[3];
    #pragma unroll
    for (int mt = 0; mt < 3; ++mt)
        #pragma unroll
        for (int r = 0; r < 4; ++r) acc[mt][r] = 0.f;

    for (int ks = 0; ks <= 64; ++ks) {   // K = 65*32 = 2080 >= 2050, rest zero
        const int kb = ks * 32 + q * 8;
        float bv[8], av[3][8];
        if (ks < 32) {                    // pure cos region (k <= 1023)
            #pragma unroll
            for (int j = 0; j < 8; ++j) {
                int k = kb + j;
                bv[j] = wcos[(size_t)k * FFTLEN + nn];
                #pragma unroll
                for (int mt = 0; mt < 3; ++mt) av[mt][j] = cs[mt] * cp[mt][k];
            }
        } else if (ks > 32 && ks < 64) {  // pure sin region (k in [1056,2047])
            int mb = kb - 1025;
            #pragma unroll
            for (int j = 0; j < 8; ++j) {
                int m = mb + j;
                bv[j] = wsin[(size_t)m * FFTLEN + nn];
                #pragma unroll
                for (int mt = 0; mt < 3; ++mt) av[mt][j] = ss[mt] * sp[mt][m];
            }
        } else {                          // boundary chunks ks==32, ks==64
            #pragma unroll
            for (int j = 0; j < 8; ++j) {
                int k = kb + j;
                float t = 0.f, a0 = 0.f, a1 = 0.f, a2 = 0.f;
                if (k <= 1024) {
                    t = wcos[(size_t)k * FFTLEN + nn];
                    a0 = cs[0] * cp[0][k]; a1 = cs[1] * cp[1][k]; a2 = cs[2] * cp[2][k];
                } else if (k <= 2049) {
                    int m = k - 1025;
                    t = wsin[(size_t)m * FFTLEN + nn];
                    a0 = ss[0] * sp[0][m]; a1 = ss[1] * sp[1][m]; a2 = ss[2] * sp[2][m];
                }
                bv[j] = t; av[0][j] = a0; av[1][j] = a1; av[2][j] = a2;
            }
        }
        bf16x8 bf = pack8(bv);
        #pragma unroll
        for (int mt = 0; mt < 3; ++mt)
            acc[mt] = __builtin_amdgcn_mfma_f32_16x16x32_bf16(pack8(av[mt]), bf, acc[mt], 0, 0, 0);
    }

    // C/D 16x16: col = lane&15 (n), row = q*4 + r
    #pragma unroll
    for (int mt = 0; mt < 3; ++mt) {
        #pragma unroll
        for (int r = 0; r < 4; ++r) {
            int row = mq * 48 + mt * 16 + q * 4 + r;
            Wp[(size_t)row * FFTLEN + nn] = f32_to_bf16(acc[mt][r]);
        }
    }
}

// ---------------- Kernel 2: main GEMM (32x32x16 MFMA) ----------------
// grid 512 x 192 (3 waves): mg = bid&1 (rows mg*96..+95), f0 = (bid>>1)*64.
// Wave w: rows mg*96 + w*32..+31, all 64 frames (nt=2 x 32). Dbuf LDS, 1 barrier/iter.
// LDS layout (ushort): off(row,k8) = row*64 + ((k8 ^ (row&7))*8)  [XOR swizzle, 2-way max]
__global__ __launch_bounds__(192) void cqt_kernel(
    const float* __restrict__ x, const unsigned short* __restrict__ Wp,
    float* __restrict__ out)
{
    __shared__ __align__(16) unsigned short Al[2][96 * 64];
    __shared__ __align__(16) unsigned short Bl[2][64 * 64];

    const int t = threadIdx.x;
    const int mg = blockIdx.x & 1;
    const int f0 = (int)(blockIdx.x >> 1) * 64;
    const int w = t / 64;
    const int l = t & 63;
    const int c32 = l & 31, h = l >> 5;

    f32x16 acc[2];
    #pragma unroll
    for (int nt = 0; nt < 2; ++nt)
        #pragma unroll
        for (int i = 0; i < 16; ++i) acc[nt][i] = 0.f;

    uint4 aR[4];
    float4 bRa[3], bRb[3];
    const bool third = (t < 128);

    auto load_chunk = [&](int kidx) {
        const int k0 = kidx * 64;
        #pragma unroll
        for (int p = 0; p < 4; ++p) {
            int e = t + p * 192;                 // < 768
            int row = e >> 3, k8 = e & 7;
            aR[p] = *(const uint4*)(Wp + (size_t)(mg * 96 + row) * FFTLEN + k0 + k8 * 8);
        }
        #pragma unroll
        for (int p = 0; p < 3; ++p) {
            if (p < 2 || third) {
                int e = t + p * 192;             // < 512
                int f = e >> 3, k8 = e & 7;
                int fi = f0 + f; if (fi > LASTF) fi = LASTF;   // clamp; masked at store
                const float* src = x + (size_t)fi * HOPS + k0 + k8 * 8;
                bRa[p] = *(const float4*)(src);
                bRb[p] = *(const float4*)(src + 4);
            }
        }
    };
    auto write_lds = [&](int buf) {
        #pragma unroll
        for (int p = 0; p < 4; ++p) {
            int e = t + p * 192;
            int row = e >> 3, k8 = e & 7;
            *(uint4*)(&Al[buf][row * 64 + ((k8 ^ (row & 7)) * 8)]) = aR[p];
        }
        #pragma unroll
        for (int p = 0; p < 3; ++p) {
            if (p < 2 || third) {
                int e = t + p * 192;
                int f = e >> 3, k8 = e & 7;
                U4B8 u;
                u.u.x = pk_bf16(bRa[p].x, bRa[p].y);
                u.u.y = pk_bf16(bRa[p].z, bRa[p].w);
                u.u.z = pk_bf16(bRb[p].x, bRb[p].y);
                u.u.w = pk_bf16(bRb[p].z, bRb[p].w);
                *(uint4*)(&Bl[buf][f * 64 + ((k8 ^ (f & 7)) * 8)]) = u.u;
            }
        }
    };
    auto compute = [&](int buf) {
        const int arow = w * 32 + c32;
        const int aswz = arow & 7;
        #pragma unroll
        for (int s16 = 0; s16 < 4; ++s16) {
            int k8 = s16 * 2 + h;
            bf16x8 af = *(const bf16x8*)(&Al[buf][arow * 64 + ((k8 ^ aswz) * 8)]);
            #pragma unroll
            for (int nt = 0; nt < 2; ++nt) {
                int fr = nt * 32 + c32;
                bf16x8 bf = *(const bf16x8*)(&Bl[buf][fr * 64 + ((k8 ^ (fr & 7)) * 8)]);
                acc[nt] = __builtin_amdgcn_mfma_f32_32x32x16_bf16(af, bf, acc[nt], 0, 0, 0);
            }
        }
    };

    load_chunk(0);
    write_lds(0);
    __syncthreads();
    load_chunk(1);

    for (int it = 0; it < 32; ++it) {
        compute(it & 1);
        if (it < 31) {
            write_lds((it + 1) & 1);
            if (it < 30) load_chunk(it + 2);
            __syncthreads();
        }
    }

    // Epilogue. C/D 32x32: col = lane&31 (f), row = (r&3) + 8*(r>>2) + 4*h.
    // Rows interleave (Wr,Wi): regs (4rp,4rp+1) -> bin b0, (4rp+2,4rp+3) -> b0+1.
    const int base = mg * 96 + w * 32 + 4 * h;   // even
    #pragma unroll
    for (int nt = 0; nt < 2; ++nt) {
        int f = f0 + nt * 32 + c32;
        if (f < NFRAMES) {
            #pragma unroll
            for (int rp = 0; rp < 4; ++rp) {
                int b0 = (base + 8 * rp) >> 1;
                float r0 = acc[nt][4 * rp + 0], i0 = acc[nt][4 * rp + 1];
                float r1 = acc[nt][4 * rp + 2], i1 = acc[nt][4 * rp + 3];
                if (b0 < NBINS)
                    out[(size_t)b0 * NFRAMES + f] = sqrtf(r0 * r0 + i0 * i0);
                if (b0 + 1 < NBINS)
                    out[(size_t)(b0 + 1) * NFRAMES + f] = sqrtf(r1 * r1 + i1 * i1);
            }
        }
    }
}

extern "C" void kernel_launch(void* const* d_in, const int* in_sizes, int n_in,
                              void* d_out, int out_size, void* d_ws, size_t ws_size,
                              hipStream_t stream) {
    const float* x    = (const float*)d_in[0];
    const float* wcos = (const float*)d_in[1];
    const float* wsin = (const float*)d_in[2];
    const float* kr   = (const float*)d_in[3];
    const float* ki   = (const float*)d_in[4];
    float* out = (float*)d_out;

    unsigned short* Wp = (unsigned short*)d_ws;   // 192*2048*2 = 786,432 B

    wgemm_kernel<<<dim3(512), dim3(64), 0, stream>>>(wcos, wsin, kr, ki, Wp);
    cqt_kernel<<<dim3(512), dim3(192), 0, stream>>>(x, Wp, out);
}

// Round 6
// 168.974 us; speedup vs baseline: 2.1521x; 1.2652x over previous
//
#include <hip/hip_runtime.h>

// CQT on gfx950 — v6: barrier-free main GEMM, x staged once per block.
//   Wr[b,n] = sum_k kr[b,k]*wcos[k,n] - ki[b,k]*wsin[k,n]
//   Wi[b,n] = sum_k kr[b,k]*wsin[k,n] + ki[b,k]*wcos[k,n]
//   cqt[b,f] = sqrt( (sum_n x[512f+n]*W[2b,n])^2 + (sum_n x[512f+n]*W[2b+1,n])^2 )
// K1 wgemm: f32 partials Pp[4][192][2048], 4-way K-split, 3072 blocks x 1 wave,
//   tile 32x16, A from kr/ki (sign/select regs), B = coalesced table rows.
// K2 wcombine: Wp[192][2048] bf16 = sum_s Pp[s].
// K3 cqt: block = 192 rows x 64 frames. x-span (34304 smp) staged ONCE to LDS bf16
//   (pad 4 shorts per 512-group: 2-way banks everywhere, b64-aligned). 12 waves
//   (6m x 2f, 32x32 tiles, mfma_32x32x16); A-frags direct from global Wp (L2);
//   ZERO barriers in the K-loop.

#define HOPS 512
#define NBINS 84
#define FREQB 1025
#define FFTLEN 2048
#define NFRAMES 16381
#define TSAMP 8388608
#define SPAN 34304            // 63*512 + 2048
#define XLSZ 34572            // SPAN + 4*67 pads

typedef short bf16x8 __attribute__((ext_vector_type(8)));
typedef float f32x4 __attribute__((ext_vector_type(4)));
typedef float f32x16 __attribute__((ext_vector_type(16)));

union B8 { struct { ushort4 lo, hi; } p; bf16x8 v; uint4 u; };

__device__ __forceinline__ unsigned short f32_to_bf16(float f) {
    union { float f; unsigned u; } v; v.f = f;
    return (unsigned short)((v.u + 0x7FFFu + ((v.u >> 16) & 1u)) >> 16);
}
__device__ __forceinline__ unsigned pk_bf16(float lo, float hi) {
    return (unsigned)f32_to_bf16(lo) | ((unsigned)f32_to_bf16(hi) << 16);
}
__device__ __forceinline__ bf16x8 pack8(const float* s) {
    B8 r;
    r.u.x = pk_bf16(s[0], s[1]); r.u.y = pk_bf16(s[2], s[3]);
    r.u.z = pk_bf16(s[4], s[5]); r.u.w = pk_bf16(s[6], s[7]);
    return r.v;
}

// ---------------- Kernel 1: W GEMM partials (4-way K-split) ----------------
// grid 3072 x 64: bid -> nb (128 n-tiles of 16), m (6 m-tiles of 32), s (4 k-splits).
// K organized as 65 chunks of 32: k<=1024 cos, 1025..2049 sin, rest zero.
// Split chunk ranges: {0..16}, {17..32}, {33..48}, {49..64} (mixed chunks 32,64 guarded).
__global__ __launch_bounds__(64) void wgemm_kernel(
    const float* __restrict__ wcos, const float* __restrict__ wsin,
    const float* __restrict__ kr, const float* __restrict__ ki,
    float* __restrict__ Pp)
{
    const int l = threadIdx.x;
    const int col = l & 15, q = l >> 4;
    const int nb = blockIdx.x & 127;
    const int rest = blockIdx.x >> 7;
    const int m = rest % 6;
    const int s = rest / 6;
    const int n0 = nb * 16, m0 = m * 32;
    const int nn = n0 + col;

    const int cs_tab[5] = {0, 17, 33, 49, 65};
    const int cstart = cs_tab[s], cend = cs_tab[s + 1];

    const float* pc[2]; const float* ps[2];
    float csg[2], ssg[2];
    #pragma unroll
    for (int mt = 0; mt < 2; ++mt) {
        int row = m0 + mt * 16 + col;
        int b = row >> 1, im = row & 1;
        float bok = (b < NBINS) ? 1.f : 0.f;
        int bc = (b < NBINS) ? b : 0;
        pc[mt] = (im ? ki : kr) + (size_t)bc * FREQB;
        ps[mt] = (im ? kr : ki) + (size_t)bc * FREQB;
        csg[mt] = bok;
        ssg[mt] = im ? bok : -bok;
    }

    f32x4 acc[2];
    #pragma unroll
    for (int mt = 0; mt < 2; ++mt)
        #pragma unroll
        for (int r = 0; r < 4; ++r) acc[mt][r] = 0.f;

    for (int c = cstart; c < cend; ++c) {
        const int kb = c * 32 + q * 8;
        float bv[8], av[2][8];
        if (c < 32) {                       // pure cos: k <= 1023
            #pragma unroll
            for (int j = 0; j < 8; ++j) {
                int k = kb + j;
                bv[j] = wcos[k * FFTLEN + nn];
                av[0][j] = csg[0] * pc[0][k];
                av[1][j] = csg[1] * pc[1][k];
            }
        } else if (c > 32 && c < 64) {      // pure sin: k in [1056, 2047]
            const int mb = kb - 1025;
            #pragma unroll
            for (int j = 0; j < 8; ++j) {
                int mm = mb + j;
                bv[j] = wsin[mm * FFTLEN + nn];
                av[0][j] = ssg[0] * ps[0][mm];
                av[1][j] = ssg[1] * ps[1][mm];
            }
        } else {                            // mixed chunks c==32, c==64
            #pragma unroll
            for (int j = 0; j < 8; ++j) {
                int k = kb + j;
                float t = 0.f, a0 = 0.f, a1 = 0.f;
                if (k <= 1024) {
                    t = wcos[k * FFTLEN + nn];
                    a0 = csg[0] * pc[0][k];
                    a1 = csg[1] * pc[1][k];
                } else if (k <= 2049) {
                    int mm = k - 1025;
                    t = wsin[mm * FFTLEN + nn];
                    a0 = ssg[0] * ps[0][mm];
                    a1 = ssg[1] * ps[1][mm];
                }
                bv[j] = t; av[0][j] = a0; av[1][j] = a1;
            }
        }
        bf16x8 bf = pack8(bv);
        #pragma unroll
        for (int mt = 0; mt < 2; ++mt)
            acc[mt] = __builtin_amdgcn_mfma_f32_16x16x32_bf16(pack8(av[mt]), bf, acc[mt], 0, 0, 0);
    }

    float* dst = Pp + (size_t)s * (192 * FFTLEN);
    #pragma unroll
    for (int mt = 0; mt < 2; ++mt)
        #pragma unroll
        for (int r = 0; r < 4; ++r) {
            int row = m0 + mt * 16 + q * 4 + r;
            dst[(size_t)row * FFTLEN + nn] = acc[mt][r];
        }
}

// ---------------- Kernel 2: combine partials -> bf16 Wp ----------------
__global__ __launch_bounds__(256) void wcombine_kernel(
    const float* __restrict__ Pp, unsigned short* __restrict__ Wp)
{
    int i = blockIdx.x * 256 + threadIdx.x;   // < 98304 float4 units
    const float4* p4 = (const float4*)Pp;
    float4 a = p4[i];
    #pragma unroll
    for (int s = 1; s < 4; ++s) {
        float4 v = p4[(size_t)s * 98304 + i];
        a.x += v.x; a.y += v.y; a.z += v.z; a.w += v.w;
    }
    ushort4 o;
    o.x = f32_to_bf16(a.x); o.y = f32_to_bf16(a.y);
    o.z = f32_to_bf16(a.z); o.w = f32_to_bf16(a.w);
    ((ushort4*)Wp)[i] = o;
}

// ---------------- Kernel 3: main GEMM, barrier-free K-loop ----------------
// grid 256 x 768 (12 waves). Block: frames f0..f0+63, all 192 rows.
// xl LDS layout: addr16(s) = s + 4*(s>>9)  [4-short pad per 512-group].
// Wave w: mg = w>>1 (rows mg*32..+31), fg = w&1 (frames fg*32..+31). mfma 32x32x16.
__global__ __launch_bounds__(768) void cqt_kernel(
    const float* __restrict__ x, const unsigned short* __restrict__ Wp,
    float* __restrict__ out)
{
    __shared__ __align__(16) unsigned short xl[XLSZ];   // 69,144 B

    const int t = threadIdx.x;
    const int f0 = blockIdx.x * 64;
    const long S0 = (long)f0 * HOPS;
    const int valid = (int)((TSAMP - S0) < (long)SPAN ? (TSAMP - S0) : (long)SPAN);

    // ---- stage x-span once: 8576 float4 over 768 threads ----
    #pragma unroll
    for (int i = 0; i < 12; ++i) {
        int idx4 = t + i * 768;
        if (idx4 < 8576) {
            int s = idx4 * 4;
            float4 v = make_float4(0.f, 0.f, 0.f, 0.f);
            if (s + 4 <= valid) v = *(const float4*)(x + S0 + s);
            ushort4 o;
            o.x = f32_to_bf16(v.x); o.y = f32_to_bf16(v.y);
            o.z = f32_to_bf16(v.z); o.w = f32_to_bf16(v.w);
            *(ushort4*)(&xl[s + 4 * (s >> 9)]) = o;     // 8B store, 2-way banks
        }
    }
    __syncthreads();   // the ONLY barrier

    const int w = t >> 6, l = t & 63;
    const int mg = w >> 1, fg = w & 1;
    const int c32 = l & 31, h = l >> 5;

    const unsigned short* ap = Wp + (size_t)(mg * 32 + c32) * FFTLEN + h * 8;
    const int sbase = (fg * 32 + c32) * HOPS + h * 8;

    f32x16 acc;
    #pragma unroll
    for (int i = 0; i < 16; ++i) acc[i] = 0.f;

    auto loadA = [&](int k16) -> bf16x8 {
        return *(const bf16x8*)(ap + k16 * 16);
    };
    auto loadB = [&](int k16) -> bf16x8 {
        int s = sbase + k16 * 16;
        int off = s + 4 * (s >> 9);
        B8 r;
        r.p.lo = *(const ushort4*)(&xl[off]);
        r.p.hi = *(const ushort4*)(&xl[off + 4]);
        return r.v;
    };

    bf16x8 a0 = loadA(0), b0 = loadB(0), a1, b1;
    #pragma unroll 4
    for (int k16 = 0; k16 < 128; k16 += 2) {
        a1 = loadA(k16 + 1); b1 = loadB(k16 + 1);
        acc = __builtin_amdgcn_mfma_f32_32x32x16_bf16(a0, b0, acc, 0, 0, 0);
        if (k16 + 2 < 128) { a0 = loadA(k16 + 2); b0 = loadB(k16 + 2); }
        acc = __builtin_amdgcn_mfma_f32_32x32x16_bf16(a1, b1, acc, 0, 0, 0);
    }

    // Epilogue. C/D 32x32: col = lane&31 (f), row = (r&3) + 8*(r>>2) + 4*h.
    // Even row base: regs (4rp, 4rp+1) -> bin b0, (4rp+2, 4rp+3) -> b0+1.
    const int f = f0 + fg * 32 + c32;
    if (f < NFRAMES) {
        #pragma unroll
        for (int rp = 0; rp < 4; ++rp) {
            int base = mg * 32 + 8 * rp + 4 * h;
            int b0 = base >> 1;
            float r0 = acc[4 * rp + 0], i0 = acc[4 * rp + 1];
            float r1 = acc[4 * rp + 2], i1 = acc[4 * rp + 3];
            if (b0 < NBINS)
                out[(size_t)b0 * NFRAMES + f] = sqrtf(r0 * r0 + i0 * i0);
            if (b0 + 1 < NBINS)
                out[(size_t)(b0 + 1) * NFRAMES + f] = sqrtf(r1 * r1 + i1 * i1);
        }
    }
}

extern "C" void kernel_launch(void* const* d_in, const int* in_sizes, int n_in,
                              void* d_out, int out_size, void* d_ws, size_t ws_size,
                              hipStream_t stream) {
    const float* x    = (const float*)d_in[0];
    const float* wcos = (const float*)d_in[1];
    const float* wsin = (const float*)d_in[2];
    const float* kr   = (const float*)d_in[3];
    const float* ki   = (const float*)d_in[4];
    float* out = (float*)d_out;

    unsigned short* Wp = (unsigned short*)d_ws;                 //   786,432 B
    float* Pp = (float*)((char*)d_ws + 786432);                 // 6,291,456 B

    wgemm_kernel<<<dim3(3072), dim3(64), 0, stream>>>(wcos, wsin, kr, ki, Pp);
    wcombine_kernel<<<dim3(384), dim3(256), 0, stream>>>(Pp, Wp);
    cqt_kernel<<<dim3(256), dim3(768), 0, stream>>>(x, Wp, out);
}

// Round 7
// 128.256 us; speedup vs baseline: 2.8353x; 1.3175x over previous
//
#include <hip/hip_runtime.h>

// CQT on gfx950 — v7: fragment-order A buffers + deep prefetch.
//   Wr[b,n] = sum_k kr[b,k]*wcos[k,n] - ki[b,k]*wsin[k,n]
//   Wi[b,n] = sum_k kr[b,k]*wsin[k,n] + ki[b,k]*wcos[k,n]
//   cqt[b,f] = sqrt((sum_n x[512f+n]*W[2b,n])^2 + (sum_n x[512f+n]*W[2b+1,n])^2)
// K1 aprep:   Apf = A'[192][2208] bf16 in MFMA-frag order [mt][k16][lane]x8.
//             A' row 2b=[kr_b | -ki_b], 2b+1=[ki_b | kr_b] (cos k<=1024, sin 1025..2049).
// K2 wgemm:   Pp[6][192][2048] f32 partials, 2304 1-wave blocks (6mt x 64nt x 6 Ksplit),
//             mfma 32x32x16; A coalesced from Apf; B = 4-full-line table reads.
// K3 combine: Wpf bf16 = sum_s Pp[s], written in frag order [mg][k16][lane]x8.
// K4 cqt:     block 192rows x 64frames, 12 waves (6mg x 2fg, 32x32 tiles), x-span
//             staged once to LDS (barrier-free K-loop), A from Wpf coalesced with
//             8-deep double-buffered register prefetch.

#define HOPS 512
#define NBINS 84
#define FREQB 1025
#define FFTLEN 2048
#define NFRAMES 16381
#define LASTF 16380
#define TSAMP 8388608
#define SPAN 34304            // 63*512 + 2048
#define XLSZ 34572            // SPAN + 4*(SPAN/512) pads
#define KP16 138              // k16 slots in wgemm K (2208)
#define WSLICE 23             // k16 per K-split
#define NSPL 6

typedef short bf16x8 __attribute__((ext_vector_type(8)));
typedef float f32x16 __attribute__((ext_vector_type(16)));

union B8 { struct { ushort4 lo, hi; } p; bf16x8 v; uint4 u; };

__device__ __forceinline__ unsigned short f32_to_bf16(float f) {
    union { float f; unsigned u; } v; v.f = f;
    return (unsigned short)((v.u + 0x7FFFu + ((v.u >> 16) & 1u)) >> 16);
}
__device__ __forceinline__ unsigned pk_bf16(float lo, float hi) {
    return (unsigned)f32_to_bf16(lo) | ((unsigned)f32_to_bf16(hi) << 16);
}
__device__ __forceinline__ bf16x8 pack8(const float* s) {
    B8 r;
    r.u.x = pk_bf16(s[0], s[1]); r.u.y = pk_bf16(s[2], s[3]);
    r.u.z = pk_bf16(s[4], s[5]); r.u.w = pk_bf16(s[6], s[7]);
    return r.v;
}

// ---------------- K1: A' prep into frag order ----------------
// grid 828 x 64: bid = mt*138 + k16. lane l: c32=l&31, h=l>>5.
// Apf[(mt*138+k16)*512 + l*8 + j] = A'[mt*32+c32][k16*16+h*8+j]
__global__ __launch_bounds__(64) void aprep_kernel(
    const float* __restrict__ kr, const float* __restrict__ ki,
    unsigned short* __restrict__ Apf)
{
    const int bid = blockIdx.x;
    const int mt = bid / KP16, k16 = bid % KP16;
    const int l = threadIdx.x;
    const int c32 = l & 31, h = l >> 5;
    const int row = mt * 32 + c32;
    const int b = row >> 1, im = row & 1;
    const bool bok = b < NBINS;
    const float* cosp = (im ? ki : kr) + (size_t)(bok ? b : 0) * FREQB;
    const float* sinp = (im ? kr : ki) + (size_t)(bok ? b : 0) * FREQB;
    const float ssign = im ? 1.f : -1.f;

    unsigned short o[8];
    #pragma unroll
    for (int j = 0; j < 8; ++j) {
        int k = k16 * 16 + h * 8 + j;
        float v = 0.f;
        if (bok) {
            if (k <= 1024)       v = cosp[k];
            else if (k <= 2049)  v = ssign * sinp[k - 1025];
        }
        o[j] = f32_to_bf16(v);
    }
    #pragma unroll
    for (int j = 0; j < 8; ++j)
        Apf[(size_t)bid * 512 + l * 8 + j] = o[j];
}

// ---------------- K2: W GEMM partials ----------------
// grid 2304 x 64: nt = bid&63, mt = (bid>>6)%6, s = bid/384. mfma 32x32x16.
// A[m][k]: m=c32 (row in mtile), k-run h*8+j  -> one uint4 from Apf (coalesced).
// B[k][n]: n=c32 (col in ntile), k-run h*8+j  -> 8 dword loads, 4 full lines each.
__global__ __launch_bounds__(64) void wgemm_kernel(
    const float* __restrict__ wcos, const float* __restrict__ wsin,
    const unsigned short* __restrict__ Apf, float* __restrict__ Pp)
{
    const int bid = blockIdx.x;
    const int nt = bid & 63;
    const int rest = bid >> 6;
    const int mt = rest % 6, s = rest / 6;
    const int l = threadIdx.x;
    const int c32 = l & 31, h = l >> 5;
    const int n = nt * 32 + c32;

    f32x16 acc;
    #pragma unroll
    for (int i = 0; i < 16; ++i) acc[i] = 0.f;

    const unsigned short* ap = Apf + (size_t)(mt * KP16 + s * WSLICE) * 512 + l * 8;

    for (int i = 0; i < WSLICE; ++i) {
        const int k16 = s * WSLICE + i;
        if (k16 > 128) break;             // zero region
        // A frag (coalesced 1KB)
        B8 af; af.u = *(const uint4*)(ap + (size_t)i * 512);
        // B frag from tables
        float bv[8];
        const int kb = k16 * 16 + h * 8;
        if (k16 <= 63) {                  // pure cos
            #pragma unroll
            for (int j = 0; j < 8; ++j)
                bv[j] = wcos[(size_t)(kb + j) * FFTLEN + n];
        } else if (k16 >= 65 && k16 <= 127) {   // pure sin
            const int mb = kb - 1025;
            #pragma unroll
            for (int j = 0; j < 8; ++j)
                bv[j] = wsin[(size_t)(mb + j) * FFTLEN + n];
        } else {                          // mixed k16==64 or 128
            #pragma unroll
            for (int j = 0; j < 8; ++j) {
                int k = kb + j;
                float t = 0.f;
                if (k <= 1024)      t = wcos[(size_t)k * FFTLEN + n];
                else if (k <= 2049) t = wsin[(size_t)(k - 1025) * FFTLEN + n];
                bv[j] = t;
            }
        }
        acc = __builtin_amdgcn_mfma_f32_32x32x16_bf16(af.v, pack8(bv), acc, 0, 0, 0);
    }

    // store partials: C/D col=c32 (n), row=(r&3)+8*(r>>2)+4*h
    float* dst = Pp + (size_t)s * (192 * FFTLEN);
    #pragma unroll
    for (int r = 0; r < 16; ++r) {
        int row = mt * 32 + (r & 3) + 8 * (r >> 2) + 4 * h;
        dst[(size_t)row * FFTLEN + n] = acc[r];
    }
}

// ---------------- K3: combine partials -> Wpf (frag order) ----------------
// grid 192 x 256. gid -> (mg, k16, l): Wpf[(mg*128+k16)*512 + l*8 + j]
//   = bf16( sum_s Pp[s][mg*32 + (l&31)][k16*16 + (l>>5)*8 + j] )
__global__ __launch_bounds__(256) void combine_kernel(
    const float* __restrict__ Pp, unsigned short* __restrict__ Wpf)
{
    const int gid = blockIdx.x * 256 + threadIdx.x;   // < 49152
    const int mg = gid >> 13;
    const int r = gid & 8191;
    const int k16 = r >> 6, l = r & 63;
    const int c32 = l & 31, h = l >> 5;
    const int row = mg * 32 + c32;
    const int n0 = k16 * 16 + h * 8;

    float4 s0 = make_float4(0.f, 0.f, 0.f, 0.f), s1 = s0;
    const float* base = Pp + (size_t)row * FFTLEN + n0;
    #pragma unroll
    for (int s = 0; s < NSPL; ++s) {
        const float* p = base + (size_t)s * (192 * FFTLEN);
        float4 a = *(const float4*)(p);
        float4 b = *(const float4*)(p + 4);
        s0.x += a.x; s0.y += a.y; s0.z += a.z; s0.w += a.w;
        s1.x += b.x; s1.y += b.y; s1.z += b.z; s1.w += b.w;
    }
    uint4 o;
    o.x = pk_bf16(s0.x, s0.y); o.y = pk_bf16(s0.z, s0.w);
    o.z = pk_bf16(s1.x, s1.y); o.w = pk_bf16(s1.z, s1.w);
    ((uint4*)Wpf)[gid] = o;
}

// ---------------- K4: main GEMM, barrier-free, deep prefetch ----------------
// grid 256 x 768. Block: frames f0..f0+63, all 192 rows. 12 waves: mg=w>>1 (32 rows),
// fg=w&1 (32 frames). mfma 32x32x16, acc 16. A from Wpf (frag order, coalesced),
// 8-step double-buffered register prefetch. B from xl LDS (pad 4/512, b64 pairs).
__global__ __launch_bounds__(768) void cqt_kernel(
    const float* __restrict__ x, const unsigned short* __restrict__ Wpf,
    float* __restrict__ out)
{
    __shared__ __align__(16) unsigned short xl[XLSZ];   // 69,144 B

    const int t = threadIdx.x;
    const int f0 = blockIdx.x * 64;
    const long S0 = (long)f0 * HOPS;
    const int valid = (int)((TSAMP - S0) < (long)SPAN ? (TSAMP - S0) : (long)SPAN);

    // stage x-span once: 8576 float4 over 768 threads
    #pragma unroll
    for (int i = 0; i < 12; ++i) {
        int idx4 = t + i * 768;
        if (idx4 < 8576) {
            int s = idx4 * 4;
            float4 v = make_float4(0.f, 0.f, 0.f, 0.f);
            if (s + 4 <= valid) v = *(const float4*)(x + S0 + s);
            ushort4 o;
            o.x = f32_to_bf16(v.x); o.y = f32_to_bf16(v.y);
            o.z = f32_to_bf16(v.z); o.w = f32_to_bf16(v.w);
            *(ushort4*)(&xl[s + 4 * (s >> 9)]) = o;
        }
    }
    __syncthreads();   // the only barrier

    const int w = t >> 6, l = t & 63;
    const int mg = w >> 1, fg = w & 1;
    const int c32 = l & 31, h = l >> 5;

    const unsigned short* apf = Wpf + (size_t)mg * (128 * 512) + l * 8;  // +k16*512
    const int sbase = (fg * 32 + c32) * HOPS + h * 8;

    f32x16 acc;
    #pragma unroll
    for (int i = 0; i < 16; ++i) acc[i] = 0.f;

    auto ldsB = [&](int k16) -> bf16x8 {
        int s = sbase + k16 * 16;
        int off = s + 4 * (s >> 9);
        B8 r;
        r.p.lo = *(const ushort4*)(&xl[off]);
        r.p.hi = *(const ushort4*)(&xl[off + 4]);
        return r.v;
    };

    uint4 Abuf[2][8];
    #pragma unroll
    for (int j = 0; j < 8; ++j)
        Abuf[0][j] = *(const uint4*)(apf + (size_t)j * 512);

    #pragma unroll
    for (int c = 0; c < 16; ++c) {
        const int cur = c & 1, nxt = cur ^ 1;
        if (c < 15) {
            #pragma unroll
            for (int j = 0; j < 8; ++j)
                Abuf[nxt][j] = *(const uint4*)(apf + (size_t)((c + 1) * 8 + j) * 512);
        }
        #pragma unroll
        for (int j = 0; j < 8; ++j) {
            B8 af; af.u = Abuf[cur][j];
            acc = __builtin_amdgcn_mfma_f32_32x32x16_bf16(af.v, ldsB(c * 8 + j), acc, 0, 0, 0);
        }
    }

    // epilogue: C/D col=c32 (f), row=(r&3)+8*(r>>2)+4*h; (Wr,Wi) pairs -> magnitude
    const int f = f0 + fg * 32 + c32;
    if (f < NFRAMES) {
        #pragma unroll
        for (int rp = 0; rp < 4; ++rp) {
            int base = mg * 32 + 8 * rp + 4 * h;   // even
            int b0 = base >> 1;
            float r0 = acc[4 * rp + 0], i0 = acc[4 * rp + 1];
            float r1 = acc[4 * rp + 2], i1 = acc[4 * rp + 3];
            if (b0 < NBINS)
                out[(size_t)b0 * NFRAMES + f] = sqrtf(r0 * r0 + i0 * i0);
            if (b0 + 1 < NBINS)
                out[(size_t)(b0 + 1) * NFRAMES + f] = sqrtf(r1 * r1 + i1 * i1);
        }
    }
}

extern "C" void kernel_launch(void* const* d_in, const int* in_sizes, int n_in,
                              void* d_out, int out_size, void* d_ws, size_t ws_size,
                              hipStream_t stream) {
    const float* x    = (const float*)d_in[0];
    const float* wcos = (const float*)d_in[1];
    const float* wsin = (const float*)d_in[2];
    const float* kr   = (const float*)d_in[3];
    const float* ki   = (const float*)d_in[4];
    float* out = (float*)d_out;

    unsigned short* Wpf = (unsigned short*)d_ws;                    //   786,432 B
    unsigned short* Apf = (unsigned short*)((char*)d_ws + 786432);  //   847,872 B
    float* Pp = (float*)((char*)d_ws + 786432 + 847872);            // 9,437,184 B (tot ~11.1 MB)

    aprep_kernel<<<dim3(6 * KP16), dim3(64), 0, stream>>>(kr, ki, Apf);
    wgemm_kernel<<<dim3(2304), dim3(64), 0, stream>>>(wcos, wsin, Apf, Pp);
    combine_kernel<<<dim3(192), dim3(256), 0, stream>>>(Pp, Wpf);
    cqt_kernel<<<dim3(256), dim3(768), 0, stream>>>(x, Wpf, out);
}